// Round 1
// baseline (497.226 us; speedup 1.0000x reference)
//
#include <hip/hip_runtime.h>

// Problem constants (P=8): weights = z @ W^T + b, shape [B*L, 81];
// out[pos] = sum_{p,k} mask(w)[p*9+k] * x0^p * x1^k.
constexpr int NW = 81;    // (P+1)^2
constexpr int KD = 256;   // n

__global__ __launch_bounds__(256, 4) void poly_kernel(
    const float* __restrict__ x,     // [npos][2]
    const float* __restrict__ z,     // [npos][256]
    const float* __restrict__ W,     // [81][256]
    const float* __restrict__ bias,  // [81]
    float* __restrict__ out,         // [npos]
    float* __restrict__ wout,        // [npos][81]
    int npos)
{
    const int pos = blockIdx.x * 256 + threadIdx.x;
    if (pos >= npos) return;

    float acc[NW];
#pragma unroll
    for (int p = 0; p < NW; ++p) acc[p] = 0.f;

    const float* zrow = z + (size_t)pos * KD;

    // GEMV per position: acc[p] += z[kk..kk+7] . W[p][kk..kk+7]
    // kk/p/j are wave-uniform -> W reads scalarize to s_load (scalar pipe).
    for (int kk = 0; kk < KD; kk += 8) {
        const float4 za = *reinterpret_cast<const float4*>(zrow + kk);
        const float4 zb = *reinterpret_cast<const float4*>(zrow + kk + 4);
        const float zr0 = za.x, zr1 = za.y, zr2 = za.z, zr3 = za.w;
        const float zr4 = zb.x, zr5 = zb.y, zr6 = zb.z, zr7 = zb.w;
#pragma unroll
        for (int p = 0; p < NW; ++p) {
            const float* wr = W + p * KD + kk;
            float a = acc[p];
            a = fmaf(zr0, wr[0], a);
            a = fmaf(zr1, wr[1], a);
            a = fmaf(zr2, wr[2], a);
            a = fmaf(zr3, wr[3], a);
            a = fmaf(zr4, wr[4], a);
            a = fmaf(zr5, wr[5], a);
            a = fmaf(zr6, wr[6], a);
            a = fmaf(zr7, wr[7], a);
            acc[p] = a;
        }
    }

    // Powers of x0, x1 (x^0 = 1 exactly).
    const float x0 = x[2 * (size_t)pos + 0];
    const float x1 = x[2 * (size_t)pos + 1];
    float px0[9], px1[9];
    px0[0] = 1.f; px1[0] = 1.f;
#pragma unroll
    for (int j = 1; j <= 8; ++j) {
        px0[j] = px0[j - 1] * x0;
        px1[j] = px1[j - 1] * x1;
    }

    float result = 0.f;
    float* wrow_out = wout + (size_t)pos * NW;
#pragma unroll
    for (int p = 0; p < 9; ++p) {
#pragma unroll
        for (int k = 0; k < 9; ++k) {
            const int idx = p * 9 + k;
            float w = acc[idx] + bias[idx];          // bias is uniform (s_load)
            if (idx == 0 || idx == 1 || idx == 9) w = 0.f;  // mask [0,0],[0,1],[1,0]
            wrow_out[idx] = w;
            result = fmaf(w, px0[p] * px1[k], result);
        }
    }
    out[pos] = result;
}

extern "C" void kernel_launch(void* const* d_in, const int* in_sizes, int n_in,
                              void* d_out, int out_size, void* d_ws, size_t ws_size,
                              hipStream_t stream) {
    const float* x = (const float*)d_in[0];
    const float* z = (const float*)d_in[1];
    const float* W = (const float*)d_in[2];
    const float* b = (const float*)d_in[3];

    const int npos = in_sizes[0] / 2;   // B*L
    float* out = (float*)d_out;         // first npos floats: out[:,:,None]
    float* wout = out + npos;           // then npos*81 floats: masked weights

    const int block = 256;
    const int grid = (npos + block - 1) / block;
    hipLaunchKernelGGL(poly_kernel, dim3(grid), dim3(block), 0, stream,
                       x, z, W, b, out, wout, npos);
}

// Round 3
// 110.092 us; speedup vs baseline: 4.5165x; 4.5165x over previous
//
#include <hip/hip_runtime.h>

// weights[M,81] = z[M,256] @ W^T[256,81] + b, masked; out[M] = sum_pk w*x0^p*x1^k
// M = B*L = 262144. fp16 MFMA GEMM, fused epilogue.

typedef _Float16 half8 __attribute__((ext_vector_type(8)));
typedef __fp16 fp16x2 __attribute__((ext_vector_type(2)));   // cvt_pkrtz return type
typedef float f32x4 __attribute__((ext_vector_type(4)));

constexpr int NW = 81;    // (P+1)^2
constexpr int KD = 256;   // n
constexpr int BM = 128;   // rows per block (4 waves x 32)
constexpr int NT = 6;     // N tiles of 16 (96 cols, cols>=81 zero-padded)
constexpr int KT = 8;     // K steps of 32

__global__ __launch_bounds__(256, 3) void poly_mfma(
    const float* __restrict__ x,     // [npos][2]
    const float* __restrict__ z,     // [npos][256]
    const float* __restrict__ W,     // [81][256]
    const float* __restrict__ bias,  // [81]
    float* __restrict__ out,         // [npos]
    float* __restrict__ wout,        // [npos][81]
    int npos)
{
    // B fragments pre-arranged: [n][kk][lane] x 8 halves (16B/lane, contiguous)
    __shared__ _Float16 Bl[NT * KT * 64 * 8];   // 49152 B

    const int tid = threadIdx.x;

    // ---- stage W -> fp16 fragments in LDS (once; no K-loop barriers) ----
    for (int i = tid; i < NT * KT * 64; i += 256) {
        const int n   = i >> 9;         // / (KT*64)
        const int rem = i & 511;
        const int kk  = rem >> 6;
        const int l   = rem & 63;
        const int col = n * 16 + (l & 15);
        const int k0  = kk * 32 + ((l >> 4) << 3);
        union { half8 v; fp16x2 p[4]; } u;
        if (col < NW) {
            const float* wp = W + col * KD + k0;
            const float4 a = *reinterpret_cast<const float4*>(wp);
            const float4 b = *reinterpret_cast<const float4*>(wp + 4);
            u.p[0] = __builtin_amdgcn_cvt_pkrtz(a.x, a.y);
            u.p[1] = __builtin_amdgcn_cvt_pkrtz(a.z, a.w);
            u.p[2] = __builtin_amdgcn_cvt_pkrtz(b.x, b.y);
            u.p[3] = __builtin_amdgcn_cvt_pkrtz(b.z, b.w);
        } else {
            u.p[0] = __builtin_amdgcn_cvt_pkrtz(0.f, 0.f);
            u.p[1] = u.p[0]; u.p[2] = u.p[0]; u.p[3] = u.p[0];
        }
        *reinterpret_cast<half8*>(&Bl[(size_t)i * 8]) = u.v;
    }
    __syncthreads();

    const int lane = tid & 63;
    const int wv   = tid >> 6;        // wave 0..3
    const int c    = lane & 15;       // column within tile / A row within tile
    const int g    = lane >> 4;       // k-group 0..3

    const int rowbase = blockIdx.x * BM + wv * 32;

    // A-load rows (clamped for tail safety; stores are predicated)
    int r0 = rowbase + c;       if (r0 >= npos) r0 = npos - 1;
    int r1 = rowbase + 16 + c;  if (r1 >= npos) r1 = npos - 1;
    const float* za = z + (size_t)r0 * KD + g * 8;
    const float* zb = z + (size_t)r1 * KD + g * 8;

    f32x4 acc0[NT], acc1[NT];
#pragma unroll
    for (int n = 0; n < NT; ++n) {
        acc0[n] = (f32x4)(0.f);
        acc1[n] = (f32x4)(0.f);
    }

    // ---- K loop: 8 steps of K=32, 12 MFMA each ----
    for (int kk = 0; kk < KT; ++kk) {
        const float4 a0 = *reinterpret_cast<const float4*>(za + kk * 32);
        const float4 a1 = *reinterpret_cast<const float4*>(za + kk * 32 + 4);
        const float4 b0 = *reinterpret_cast<const float4*>(zb + kk * 32);
        const float4 b1 = *reinterpret_cast<const float4*>(zb + kk * 32 + 4);

        union { half8 v; fp16x2 p[4]; } uA, uB;
        uA.p[0] = __builtin_amdgcn_cvt_pkrtz(a0.x, a0.y);
        uA.p[1] = __builtin_amdgcn_cvt_pkrtz(a0.z, a0.w);
        uA.p[2] = __builtin_amdgcn_cvt_pkrtz(a1.x, a1.y);
        uA.p[3] = __builtin_amdgcn_cvt_pkrtz(a1.z, a1.w);
        uB.p[0] = __builtin_amdgcn_cvt_pkrtz(b0.x, b0.y);
        uB.p[1] = __builtin_amdgcn_cvt_pkrtz(b0.z, b0.w);
        uB.p[2] = __builtin_amdgcn_cvt_pkrtz(b1.x, b1.y);
        uB.p[3] = __builtin_amdgcn_cvt_pkrtz(b1.z, b1.w);
        const half8 A0 = uA.v;
        const half8 A1 = uB.v;

#pragma unroll
        for (int n = 0; n < NT; ++n) {
            const half8 Bf = *reinterpret_cast<const half8*>(
                &Bl[(size_t)((n * KT + kk) * 64 + lane) * 8]);
            acc0[n] = __builtin_amdgcn_mfma_f32_16x16x32_f16(A0, Bf, acc0[n], 0, 0, 0);
            acc1[n] = __builtin_amdgcn_mfma_f32_16x16x32_f16(A1, Bf, acc1[n], 0, 0, 0);
        }
    }

    // ---- epilogue: bias, mask, store wout, fused out-reduction ----
    // C/D layout: col = lane&15 (=c), row = g*4 + reg within the 16-row tile.
#pragma unroll
    for (int t = 0; t < 2; ++t) {
#pragma unroll
        for (int reg = 0; reg < 4; ++reg) {
            const int pos = rowbase + t * 16 + g * 4 + reg;
            const bool vp = pos < npos;
            const int cpos = vp ? pos : npos - 1;
            const float x0 = x[2 * (size_t)cpos];
            const float x1 = x[2 * (size_t)cpos + 1];
            const float x0_2 = x0 * x0, x0_4 = x0_2 * x0_2, x0_8 = x0_4 * x0_4;
            const float x1_2 = x1 * x1, x1_4 = x1_2 * x1_2, x1_8 = x1_4 * x1_4;
            float wsum = 0.f;
#pragma unroll
            for (int n = 0; n < NT; ++n) {
                const int idx = n * 16 + c;
                const float a = (t == 0) ? acc0[n][reg] : acc1[n][reg];
                if (idx < NW) {
                    float wval = a + bias[idx];
                    if (idx == 0 || idx == 1 || idx == 9) wval = 0.f;
                    if (vp) wout[(size_t)pos * NW + idx] = wval;
                    const int p  = idx / 9;
                    const int kq = idx - 9 * p;
                    const float q0 = ((p & 1) ? x0 : 1.f) * ((p & 2) ? x0_2 : 1.f)
                                   * ((p & 4) ? x0_4 : 1.f) * ((p & 8) ? x0_8 : 1.f);
                    const float q1 = ((kq & 1) ? x1 : 1.f) * ((kq & 2) ? x1_2 : 1.f)
                                   * ((kq & 4) ? x1_4 : 1.f) * ((kq & 8) ? x1_8 : 1.f);
                    wsum = fmaf(wval, q0 * q1, wsum);
                }
            }
            // reduce over the 16 lanes (columns) sharing this row
            wsum += __shfl_xor(wsum, 1, 64);
            wsum += __shfl_xor(wsum, 2, 64);
            wsum += __shfl_xor(wsum, 4, 64);
            wsum += __shfl_xor(wsum, 8, 64);
            if (c == 0 && vp) out[pos] = wsum;
        }
    }
}

extern "C" void kernel_launch(void* const* d_in, const int* in_sizes, int n_in,
                              void* d_out, int out_size, void* d_ws, size_t ws_size,
                              hipStream_t stream) {
    const float* x = (const float*)d_in[0];
    const float* z = (const float*)d_in[1];
    const float* W = (const float*)d_in[2];
    const float* b = (const float*)d_in[3];

    const int npos = in_sizes[0] / 2;   // B*L
    float* out  = (float*)d_out;        // [npos]
    float* wout = out + npos;           // [npos][81]

    const int grid = (npos + BM - 1) / BM;
    hipLaunchKernelGGL(poly_mfma, dim3(grid), dim3(256), 0, stream,
                       x, z, W, b, out, wout, npos);
}